// Round 2
// baseline (207.472 us; speedup 1.0000x reference)
//
#include <hip/hip_runtime.h>

// Problem constants
#define N_TOK 8192
#define N_EXP 8
#define DIM   2048
#define HID   2048

typedef __attribute__((ext_vector_type(8))) short short8;
typedef __attribute__((ext_vector_type(4))) float f32x4;
typedef __attribute__((ext_vector_type(4))) unsigned short ushort4v;

__device__ inline unsigned short f2bf(float f) {
  unsigned int u = __builtin_bit_cast(unsigned int, f);
  unsigned int r = u + 0x7FFFu + ((u >> 16) & 1u);   // round-to-nearest-even
  return (unsigned short)(r >> 16);
}

// ---------------------------------------------------------------------------
// Kernel 1: stable counting sort by expert id. One block, 256 threads.
// ---------------------------------------------------------------------------
__global__ __launch_bounds__(256) void sort_experts(const int* __restrict__ idx,
                                                    int* __restrict__ perm,
                                                    int* __restrict__ offs) {
  __shared__ int cnt[256][8];
  __shared__ int base[8];
  const int t = threadIdx.x;
  int local[8] = {0,0,0,0,0,0,0,0};
  const int r0 = t * 32;
  for (int i = 0; i < 32; ++i) {
    int e = idx[r0 + i] & 7;
    ++local[e];
  }
#pragma unroll
  for (int e = 0; e < 8; ++e) cnt[t][e] = local[e];
  __syncthreads();
  if (t < 8) {
    int s = 0;
    for (int i = 0; i < 256; ++i) { int v = cnt[i][t]; cnt[i][t] = s; s += v; }
    base[t] = s;
  }
  __syncthreads();
  if (t == 0) {
    int s = 0;
    for (int e = 0; e < 8; ++e) { int v = base[e]; offs[e] = s; base[e] = s; s += v; }
    offs[8] = s;
  }
  __syncthreads();
  int pos[8];
#pragma unroll
  for (int e = 0; e < 8; ++e) pos[e] = base[e] + cnt[t][e];
  for (int i = 0; i < 32; ++i) {
    int r = r0 + i;
    int e = idx[r] & 7;
    perm[pos[e]++] = r;
  }
}

// ---------------------------------------------------------------------------
// Kernel 2: gather rows into sorted order + fp32 -> bf16.
// ---------------------------------------------------------------------------
__global__ __launch_bounds__(256) void gather_convert_x(const float* __restrict__ x,
                                                        const int* __restrict__ perm,
                                                        unsigned short* __restrict__ xs) {
  int gid = blockIdx.x * 256 + threadIdx.x;
  int p = gid >> 8;
  int c = gid & 255;
  int src = perm[p];
  const float* sp = x + (size_t)src * DIM + c * 8;
  float4 a = *(const float4*)sp;
  float4 b = *(const float4*)(sp + 4);
  short8 o;
  o[0] = (short)f2bf(a.x); o[1] = (short)f2bf(a.y);
  o[2] = (short)f2bf(a.z); o[3] = (short)f2bf(a.w);
  o[4] = (short)f2bf(b.x); o[5] = (short)f2bf(b.y);
  o[6] = (short)f2bf(b.z); o[7] = (short)f2bf(b.w);
  *(short8*)(xs + (size_t)p * DIM + c * 8) = o;
}

// ---------------------------------------------------------------------------
// Kernel 3: W[e][d][h] fp32 -> Wt[e][h][d] bf16 (LDS-tiled transpose).
// ---------------------------------------------------------------------------
__global__ __launch_bounds__(256) void transpose_convert_w(const float* __restrict__ W,
                                                           unsigned short* __restrict__ Wt) {
  __shared__ unsigned short tile[64][68];
  const int e = blockIdx.z;
  const int d0 = blockIdx.y * 64;
  const int h0 = blockIdx.x * 64;
  const int t = threadIdx.x;
  const int cr = t & 15;
  const int rr = t >> 4;
  const float* Wp = W + ((size_t)e * DIM + d0) * HID + h0;
#pragma unroll
  for (int i = 0; i < 4; ++i) {
    int d = rr + i * 16;
    float4 v = *(const float4*)(Wp + (size_t)d * HID + cr * 4);
    ushort4v o;
    o[0] = f2bf(v.x); o[1] = f2bf(v.y); o[2] = f2bf(v.z); o[3] = f2bf(v.w);
    *(ushort4v*)&tile[d][cr * 4] = o;
  }
  __syncthreads();
  unsigned short* op = Wt + ((size_t)e * HID + h0) * DIM + d0;
#pragma unroll
  for (int i = 0; i < 4; ++i) {
    int h = rr + i * 16;
    ushort4v o;
    o[0] = tile[cr * 4 + 0][h];
    o[1] = tile[cr * 4 + 1][h];
    o[2] = tile[cr * 4 + 2][h];
    o[3] = tile[cr * 4 + 3][h];
    *(ushort4v*)(op + (size_t)h * DIM + cr * 4) = o;
  }
}

// ---------------------------------------------------------------------------
// Kernel 4: grouped GEMM, 256x256 tile, BK=32, 8 waves (2Mx4N), counted-vmcnt
// multi-phase pipeline (T3+T4), XOR-swizzled LDS (T2), setprio (T5).
// 4 K-tile LDS buffers (128 KiB). Prefetch 3 tiles ahead; vmcnt(8) per tile.
// ---------------------------------------------------------------------------
#define BM 256
#define BN 256
#define BK 32
#define NTILE (DIM / BK)   // 64

__global__ __launch_bounds__(512, 2) void grouped_gemm(
    const unsigned short* __restrict__ xs,
    const unsigned short* __restrict__ Wt,
    const float* __restrict__ bias,
    const int* __restrict__ offs,
    float* __restrict__ out) {
  const int e   = blockIdx.z;
  const int off = offs[e];
  const int cnt = offs[e + 1] - off;
  const int mt  = blockIdx.y;
  if (mt * BM >= cnt) return;
  const int n0 = blockIdx.x * BN;

  // [buf 0..3][op A/B][8192 ushort = 16KB]
  __shared__ __align__(16) unsigned short sm[4 * 2 * 8192];

  const int t    = threadIdx.x;
  const int lane = t & 63;
  const int wid  = t >> 6;
  const int wr   = wid >> 2;   // 0..1  (M half)
  const int wc   = wid & 3;    // 0..3  (N quarter)
  const int l15  = lane & 15;
  const int l4   = lane >> 4;

  // Swizzled fragment LDS offsets (ushort units). Rows are 64B; swizzle
  // XORs byte bits [5:4] with bits [8:7] (involution, bank-spreading).
  int aOff0, aOff1, aOff2, aOff3, aOff4, aOff5, aOff6, aOff7;
  int bOff0, bOff1, bOff2, bOff3;
  {
    int ao[8], bo[4];
#pragma unroll
    for (int m = 0; m < 8; ++m) {
      int row = wr * 128 + m * 16 + l15;
      int o = row * 64 + l4 * 16;
      o ^= ((o >> 7) & 3) << 4;
      ao[m] = o >> 1;
    }
#pragma unroll
    for (int n = 0; n < 4; ++n) {
      int col = wc * 64 + n * 16 + l15;
      int o = col * 64 + l4 * 16;
      o ^= ((o >> 7) & 3) << 4;
      bo[n] = o >> 1;
    }
    aOff0=ao[0]; aOff1=ao[1]; aOff2=ao[2]; aOff3=ao[3];
    aOff4=ao[4]; aOff5=ao[5]; aOff6=ao[6]; aOff7=ao[7];
    bOff0=bo[0]; bOff1=bo[1]; bOff2=bo[2]; bOff3=bo[3];
  }

  // Staging: chunk = 16KB = 2 x (512 threads x 16B). LDS dest is linear
  // (global_load_lds); apply INVERSE swizzle to the global source so a
  // swizzled read sees logical layout (rule 21; swizzle is an involution).
  const size_t WtE = (size_t)e * DIM * HID;
  const int aBase = off + mt * BM;
  size_t sA0, sA1, sB0, sB1;
  int ldsOff0, ldsOff1;
  {
    size_t sa[2], sb[2]; int lo[2];
#pragma unroll
    for (int c = 0; c < 2; ++c) {
      int o  = (c * 512 + t) * 16;
      int so = o ^ (((o >> 7) & 3) << 4);
      int row = so >> 6;          // 0..255
      int kb  = (so & 63) >> 1;   // k element 0..31
      int p = aBase + row; if (p > N_TOK - 1) p = N_TOK - 1;
      sa[c] = (size_t)p * DIM + kb;
      sb[c] = WtE + (size_t)(n0 + row) * DIM + kb;
      lo[c] = (c * 512 + t) * 8;  // ushort idx within chunk
    }
    sA0 = sa[0]; sA1 = sa[1]; sB0 = sb[0]; sB1 = sb[1];
    ldsOff0 = lo[0]; ldsOff1 = lo[1];
  }

  auto stageA = [&](int T_) {
    int bsl = (T_ & 3) * 2;
    int kofs = T_ * BK;
    __builtin_amdgcn_global_load_lds(
        (const __attribute__((address_space(1))) void*)(xs + sA0 + kofs),
        (__attribute__((address_space(3))) void*)(sm + bsl * 8192 + ldsOff0), 16, 0, 0);
    __builtin_amdgcn_global_load_lds(
        (const __attribute__((address_space(1))) void*)(xs + sA1 + kofs),
        (__attribute__((address_space(3))) void*)(sm + bsl * 8192 + ldsOff1), 16, 0, 0);
  };
  auto stageB = [&](int T_) {
    int bsl = (T_ & 3) * 2 + 1;
    int kofs = T_ * BK;
    __builtin_amdgcn_global_load_lds(
        (const __attribute__((address_space(1))) void*)(Wt + sB0 + kofs),
        (__attribute__((address_space(3))) void*)(sm + bsl * 8192 + ldsOff0), 16, 0, 0);
    __builtin_amdgcn_global_load_lds(
        (const __attribute__((address_space(1))) void*)(Wt + sB1 + kofs),
        (__attribute__((address_space(3))) void*)(sm + bsl * 8192 + ldsOff1), 16, 0, 0);
  };

  f32x4 acc[8][4] = {};

  // Prologue: stage tiles 0,1,2 (chunks in monotone order A0,B0,A1,B1,A2,B2).
  stageA(0); stageB(0); stageA(1); stageB(1); stageA(2); stageB(2);
  // 12 loads/wave issued; wait all but 8 -> tile 0 (chunks 0,1) landed.
  asm volatile("s_waitcnt vmcnt(8)" ::: "memory");
  __builtin_amdgcn_s_barrier();

  short8 b0, b1, b2, b3;
  for (int T = 0; T < NTILE; ++T) {
    const unsigned short* LA = sm + (T & 3) * 16384;
    const unsigned short* LB = LA + 8192;
    short8 a0, a1, a2, a3;

    // ---- phase A: m 0..3, read B frags (kept for phase B) ----
    a0 = *(const short8*)(LA + aOff0);
    a1 = *(const short8*)(LA + aOff1);
    a2 = *(const short8*)(LA + aOff2);
    a3 = *(const short8*)(LA + aOff3);
    b0 = *(const short8*)(LB + bOff0);
    b1 = *(const short8*)(LB + bOff1);
    b2 = *(const short8*)(LB + bOff2);
    b3 = *(const short8*)(LB + bOff3);
    if (T < NTILE - 3) stageA(T + 3);   // slot (T+3)&3 freed at T-1 phase B
    __builtin_amdgcn_s_barrier();
    __builtin_amdgcn_s_setprio(1);
    acc[0][0] = __builtin_amdgcn_mfma_f32_16x16x32_bf16(a0, b0, acc[0][0], 0, 0, 0);
    acc[0][1] = __builtin_amdgcn_mfma_f32_16x16x32_bf16(a0, b1, acc[0][1], 0, 0, 0);
    acc[0][2] = __builtin_amdgcn_mfma_f32_16x16x32_bf16(a0, b2, acc[0][2], 0, 0, 0);
    acc[0][3] = __builtin_amdgcn_mfma_f32_16x16x32_bf16(a0, b3, acc[0][3], 0, 0, 0);
    acc[1][0] = __builtin_amdgcn_mfma_f32_16x16x32_bf16(a1, b0, acc[1][0], 0, 0, 0);
    acc[1][1] = __builtin_amdgcn_mfma_f32_16x16x32_bf16(a1, b1, acc[1][1], 0, 0, 0);
    acc[1][2] = __builtin_amdgcn_mfma_f32_16x16x32_bf16(a1, b2, acc[1][2], 0, 0, 0);
    acc[1][3] = __builtin_amdgcn_mfma_f32_16x16x32_bf16(a1, b3, acc[1][3], 0, 0, 0);
    acc[2][0] = __builtin_amdgcn_mfma_f32_16x16x32_bf16(a2, b0, acc[2][0], 0, 0, 0);
    acc[2][1] = __builtin_amdgcn_mfma_f32_16x16x32_bf16(a2, b1, acc[2][1], 0, 0, 0);
    acc[2][2] = __builtin_amdgcn_mfma_f32_16x16x32_bf16(a2, b2, acc[2][2], 0, 0, 0);
    acc[2][3] = __builtin_amdgcn_mfma_f32_16x16x32_bf16(a2, b3, acc[2][3], 0, 0, 0);
    acc[3][0] = __builtin_amdgcn_mfma_f32_16x16x32_bf16(a3, b0, acc[3][0], 0, 0, 0);
    acc[3][1] = __builtin_amdgcn_mfma_f32_16x16x32_bf16(a3, b1, acc[3][1], 0, 0, 0);
    acc[3][2] = __builtin_amdgcn_mfma_f32_16x16x32_bf16(a3, b2, acc[3][2], 0, 0, 0);
    acc[3][3] = __builtin_amdgcn_mfma_f32_16x16x32_bf16(a3, b3, acc[3][3], 0, 0, 0);
    __builtin_amdgcn_s_setprio(0);
    __builtin_amdgcn_s_barrier();

    // ---- phase B: m 4..7, reuse B frags ----
    a0 = *(const short8*)(LA + aOff4);
    a1 = *(const short8*)(LA + aOff5);
    a2 = *(const short8*)(LA + aOff6);
    a3 = *(const short8*)(LA + aOff7);
    if (T < NTILE - 3) stageB(T + 3);
    __builtin_amdgcn_s_barrier();
    __builtin_amdgcn_s_setprio(1);
    acc[4][0] = __builtin_amdgcn_mfma_f32_16x16x32_bf16(a0, b0, acc[4][0], 0, 0, 0);
    acc[4][1] = __builtin_amdgcn_mfma_f32_16x16x32_bf16(a0, b1, acc[4][1], 0, 0, 0);
    acc[4][2] = __builtin_amdgcn_mfma_f32_16x16x32_bf16(a0, b2, acc[4][2], 0, 0, 0);
    acc[4][3] = __builtin_amdgcn_mfma_f32_16x16x32_bf16(a0, b3, acc[4][3], 0, 0, 0);
    acc[5][0] = __builtin_amdgcn_mfma_f32_16x16x32_bf16(a1, b0, acc[5][0], 0, 0, 0);
    acc[5][1] = __builtin_amdgcn_mfma_f32_16x16x32_bf16(a1, b1, acc[5][1], 0, 0, 0);
    acc[5][2] = __builtin_amdgcn_mfma_f32_16x16x32_bf16(a1, b2, acc[5][2], 0, 0, 0);
    acc[5][3] = __builtin_amdgcn_mfma_f32_16x16x32_bf16(a1, b3, acc[5][3], 0, 0, 0);
    acc[6][0] = __builtin_amdgcn_mfma_f32_16x16x32_bf16(a2, b0, acc[6][0], 0, 0, 0);
    acc[6][1] = __builtin_amdgcn_mfma_f32_16x16x32_bf16(a2, b1, acc[6][1], 0, 0, 0);
    acc[6][2] = __builtin_amdgcn_mfma_f32_16x16x32_bf16(a2, b2, acc[6][2], 0, 0, 0);
    acc[6][3] = __builtin_amdgcn_mfma_f32_16x16x32_bf16(a2, b3, acc[6][3], 0, 0, 0);
    acc[7][0] = __builtin_amdgcn_mfma_f32_16x16x32_bf16(a3, b0, acc[7][0], 0, 0, 0);
    acc[7][1] = __builtin_amdgcn_mfma_f32_16x16x32_bf16(a3, b1, acc[7][1], 0, 0, 0);
    acc[7][2] = __builtin_amdgcn_mfma_f32_16x16x32_bf16(a3, b2, acc[7][2], 0, 0, 0);
    acc[7][3] = __builtin_amdgcn_mfma_f32_16x16x32_bf16(a3, b3, acc[7][3], 0, 0, 0);
    __builtin_amdgcn_s_setprio(0);
    // Counted wait (once per K-tile): guarantee tile T+1 fully landed
    // before any wave reads it after the barrier. Never 0 in main loop.
    if (T < NTILE - 3)       { asm volatile("s_waitcnt vmcnt(8)" ::: "memory"); }
    else if (T == NTILE - 3) { asm volatile("s_waitcnt vmcnt(4)" ::: "memory"); }
    else if (T == NTILE - 2) { asm volatile("s_waitcnt vmcnt(0)" ::: "memory"); }
    __builtin_amdgcn_s_barrier();
  }

  // Epilogue: bias + relu, masked tail rows.
#pragma unroll
  for (int n = 0; n < 4; ++n) {
    int col = n0 + wc * 64 + n * 16 + l15;
    float bv = bias[e * HID + col];
#pragma unroll
    for (int m = 0; m < 8; ++m) {
#pragma unroll
      for (int q = 0; q < 4; ++q) {
        int r = wr * 128 + m * 16 + l4 * 4 + q;
        if (mt * BM + r < cnt) {
          float v = acc[m][n][q] + bv;
          out[(size_t)(off + mt * BM + r) * HID + col] = v > 0.f ? v : 0.f;
        }
      }
    }
  }
}

// ---------------------------------------------------------------------------
extern "C" void kernel_launch(void* const* d_in, const int* in_sizes, int n_in,
                              void* d_out, int out_size, void* d_ws, size_t ws_size,
                              hipStream_t stream) {
  const float* x   = (const float*)d_in[0];
  const int*   idx = (const int*)d_in[1];
  const float* W   = (const float*)d_in[2];
  const float* b   = (const float*)d_in[3];
  float* out = (float*)d_out;

  char* ws = (char*)d_ws;
  unsigned short* xs = (unsigned short*)ws;                                   // 32 MB
  unsigned short* Wt = (unsigned short*)(ws + (size_t)N_TOK * DIM * 2);       // 64 MB
  int* perm = (int*)(ws + (size_t)N_TOK * DIM * 2 + (size_t)N_EXP * DIM * HID * 2);
  int* offs = perm + N_TOK;

  sort_experts<<<1, 256, 0, stream>>>(idx, perm, offs);
  gather_convert_x<<<N_TOK * (DIM / 8) / 256, 256, 0, stream>>>(x, perm, xs);
  transpose_convert_w<<<dim3(HID / 64, DIM / 64, N_EXP), 256, 0, stream>>>(W, Wt);
  grouped_gemm<<<dim3(HID / BN, N_TOK / BM, N_EXP), 512, 0, stream>>>(xs, Wt, b, offs, out);
}

// Round 3
// 195.832 us; speedup vs baseline: 1.0594x; 1.0594x over previous
//
#include <hip/hip_runtime.h>

// Problem constants
#define N_TOK 8192
#define N_EXP 8
#define DIM   2048
#define HID   2048

typedef __attribute__((ext_vector_type(8))) short short8;
typedef __attribute__((ext_vector_type(4))) float f32x4;
typedef __attribute__((ext_vector_type(4))) unsigned short ushort4v;

__device__ inline unsigned short f2bf(float f) {
  unsigned int u = __builtin_bit_cast(unsigned int, f);
  unsigned int r = u + 0x7FFFu + ((u >> 16) & 1u);   // round-to-nearest-even
  return (unsigned short)(r >> 16);
}

// ---------------------------------------------------------------------------
// Kernel 1: stable counting sort by expert id. One block, 256 threads.
// ---------------------------------------------------------------------------
__global__ __launch_bounds__(256) void sort_experts(const int* __restrict__ idx,
                                                    int* __restrict__ perm,
                                                    int* __restrict__ offs) {
  __shared__ int cnt[256][8];
  __shared__ int base[8];
  const int t = threadIdx.x;
  int local[8] = {0,0,0,0,0,0,0,0};
  const int r0 = t * 32;
  for (int i = 0; i < 32; ++i) {
    int e = idx[r0 + i] & 7;
    ++local[e];
  }
#pragma unroll
  for (int e = 0; e < 8; ++e) cnt[t][e] = local[e];
  __syncthreads();
  if (t < 8) {
    int s = 0;
    for (int i = 0; i < 256; ++i) { int v = cnt[i][t]; cnt[i][t] = s; s += v; }
    base[t] = s;
  }
  __syncthreads();
  if (t == 0) {
    int s = 0;
    for (int e = 0; e < 8; ++e) { int v = base[e]; offs[e] = s; base[e] = s; s += v; }
    offs[8] = s;
  }
  __syncthreads();
  int pos[8];
#pragma unroll
  for (int e = 0; e < 8; ++e) pos[e] = base[e] + cnt[t][e];
  for (int i = 0; i < 32; ++i) {
    int r = r0 + i;
    int e = idx[r] & 7;
    perm[pos[e]++] = r;
  }
}

// ---------------------------------------------------------------------------
// Kernel 2: gather rows into sorted order + fp32 -> bf16.
// ---------------------------------------------------------------------------
__global__ __launch_bounds__(256) void gather_convert_x(const float* __restrict__ x,
                                                        const int* __restrict__ perm,
                                                        unsigned short* __restrict__ xs) {
  int gid = blockIdx.x * 256 + threadIdx.x;
  int p = gid >> 8;
  int c = gid & 255;
  int src = perm[p];
  const float* sp = x + (size_t)src * DIM + c * 8;
  float4 a = *(const float4*)sp;
  float4 b = *(const float4*)(sp + 4);
  short8 o;
  o[0] = (short)f2bf(a.x); o[1] = (short)f2bf(a.y);
  o[2] = (short)f2bf(a.z); o[3] = (short)f2bf(a.w);
  o[4] = (short)f2bf(b.x); o[5] = (short)f2bf(b.y);
  o[6] = (short)f2bf(b.z); o[7] = (short)f2bf(b.w);
  *(short8*)(xs + (size_t)p * DIM + c * 8) = o;
}

// ---------------------------------------------------------------------------
// Kernel 3: W[e][d][h] fp32 -> Wt[e][h][d] bf16 (LDS-tiled transpose).
// ---------------------------------------------------------------------------
__global__ __launch_bounds__(256) void transpose_convert_w(const float* __restrict__ W,
                                                           unsigned short* __restrict__ Wt) {
  __shared__ unsigned short tile[64][68];
  const int e = blockIdx.z;
  const int d0 = blockIdx.y * 64;
  const int h0 = blockIdx.x * 64;
  const int t = threadIdx.x;
  const int cr = t & 15;
  const int rr = t >> 4;
  const float* Wp = W + ((size_t)e * DIM + d0) * HID + h0;
#pragma unroll
  for (int i = 0; i < 4; ++i) {
    int d = rr + i * 16;
    float4 v = *(const float4*)(Wp + (size_t)d * HID + cr * 4);
    ushort4v o;
    o[0] = f2bf(v.x); o[1] = f2bf(v.y); o[2] = f2bf(v.z); o[3] = f2bf(v.w);
    *(ushort4v*)&tile[d][cr * 4] = o;
  }
  __syncthreads();
  unsigned short* op = Wt + ((size_t)e * HID + h0) * DIM + d0;
#pragma unroll
  for (int i = 0; i < 4; ++i) {
    int h = rr + i * 16;
    ushort4v o;
    o[0] = tile[cr * 4 + 0][h];
    o[1] = tile[cr * 4 + 1][h];
    o[2] = tile[cr * 4 + 2][h];
    o[3] = tile[cr * 4 + 3][h];
    *(ushort4v*)(op + (size_t)h * DIM + cr * 4) = o;
  }
}

// ---------------------------------------------------------------------------
// Kernel 4: grouped GEMM — faithful 8-phase template (m201 lineage).
// 256x256 tile, BK=64, 2 K-tiles/iter in 2 LDS slots (128 KiB), 8 waves
// (2M x 4N, per-wave 128x64). Per phase: {ds_read frags | stage 1 half-tile
// (2 gload_lds) | barrier | setprio1 | 16 MFMA | setprio0 | barrier}.
// vmcnt(4) only at phases 4 and 8 (2 half-tiles in flight). XOR swizzle:
// byte bits[6:4] ^= row[2:0] (per-lane constant), conflict-free reads.
// ---------------------------------------------------------------------------
#define NK    32    // K-tiles of 64
#define NITER 16    // 2 K-tiles per iteration

#define MM(D,A,B) D = __builtin_amdgcn_mfma_f32_16x16x32_bf16(A, B, D, 0, 0, 0)
#define GLD(SRC, DST) __builtin_amdgcn_global_load_lds( \
    (const __attribute__((address_space(1))) void*)(SRC), \
    (__attribute__((address_space(3))) void*)(DST), 16, 0, 0)
#define BAR() __builtin_amdgcn_s_barrier()
#define PRIO(x) __builtin_amdgcn_s_setprio(x)

// Stage A quarter-pair Q (rows c*128 + Q*64 + [0,64)) of tile at k-elem KOFS
#define ST_A(SLOT,Q,KOFS) do { \
    GLD(xs + paw0##Q + (KOFS), sm + (SLOT)*32768 + (Q)*4096 + 0*8192 + dA); \
    GLD(xs + paw1##Q + (KOFS), sm + (SLOT)*32768 + (Q)*4096 + 1*8192 + dA); } while(0)
// Stage B half HH (rows HH*128 + c*64 + [0,64))
#define ST_B(SLOT,HH,KOFS) do { \
    GLD(Wt + pbw0##HH + (KOFS), sm + (SLOT)*32768 + 16384 + (HH)*8192 + 0*4096 + dA); \
    GLD(Wt + pbw1##HH + (KOFS), sm + (SLOT)*32768 + 16384 + (HH)*8192 + 1*4096 + dA); } while(0)

#define READ_A(LS, MH, CB) \
    fa0 = *(const short8*)((LS) + arow + ((MH)*4+0)*1024 + (CB)); \
    fa1 = *(const short8*)((LS) + arow + ((MH)*4+1)*1024 + (CB)); \
    fa2 = *(const short8*)((LS) + arow + ((MH)*4+2)*1024 + (CB)); \
    fa3 = *(const short8*)((LS) + arow + ((MH)*4+3)*1024 + (CB));

#define READ_B(LS, CB, B0,B1,B2,B3) \
    B0 = *(const short8*)((LS) + brow + 0*1024 + (CB)); \
    B1 = *(const short8*)((LS) + brow + 1*1024 + (CB)); \
    B2 = *(const short8*)((LS) + brow + 2*1024 + (CB)); \
    B3 = *(const short8*)((LS) + brow + 3*1024 + (CB));

#define QUAD(MB, B0,B1,B2,B3) \
    MM(acc[MB+0][0],fa0,B0); MM(acc[MB+0][1],fa0,B1); MM(acc[MB+0][2],fa0,B2); MM(acc[MB+0][3],fa0,B3); \
    MM(acc[MB+1][0],fa1,B0); MM(acc[MB+1][1],fa1,B1); MM(acc[MB+1][2],fa1,B2); MM(acc[MB+1][3],fa1,B3); \
    MM(acc[MB+2][0],fa2,B0); MM(acc[MB+2][1],fa2,B1); MM(acc[MB+2][2],fa2,B2); MM(acc[MB+2][3],fa2,B3); \
    MM(acc[MB+3][0],fa3,B0); MM(acc[MB+3][1],fa3,B1); MM(acc[MB+3][2],fa3,B2); MM(acc[MB+3][3],fa3,B3);

__global__ __launch_bounds__(512, 2) void grouped_gemm(
    const unsigned short* __restrict__ xs,
    const unsigned short* __restrict__ Wt,
    const float* __restrict__ bias,
    const int* __restrict__ offs,
    float* __restrict__ out) {
  const int e   = blockIdx.z;
  const int off = offs[e];
  const int cnt = offs[e + 1] - off;
  const int mt  = blockIdx.y;
  if (mt * 256 >= cnt) return;
  const int n0 = blockIdx.x * 256;

  __shared__ __align__(16) unsigned short sm[65536];   // 2 slots x (A 32KB + B 32KB)

  const int t    = threadIdx.x;
  const int lane = t & 63;
  const int wid  = t >> 6;
  const int wr   = wid >> 2;   // 0..1
  const int wc   = wid & 3;    // 0..3
  const int l15  = lane & 15;
  const int l4   = lane >> 4;

  // Fragment LDS offsets (ushort units). Row stride 64 ushorts (128B).
  // Swizzle: byte bits[6:4] ^= row[2:0]; row[2:0] == l15&7 for all frags.
  const int cb0  = (l4 * 8) ^ ((l15 & 7) << 3);   // ksub 0
  const int cb1  = cb0 ^ 32;                       // ksub 1
  const int arow = (wr * 128 + l15) * 64;
  const int brow = 16384 + (wc * 64 + l15) * 64;

  // Staging source addresses. Chunk thread t covers row r0=t>>3, 16B col
  // (t&7)*16 within a 64-row chunk; pre-apply inverse swizzle to source.
  const int r0  = t >> 3;
  const int keu = ((t & 7) * 8) ^ ((r0 & 7) << 3);   // swizzled k-elem
  const int aBase = off + mt * 256;
  const int dA = t * 8;   // linear LDS dest (ushort) within chunk

  unsigned int paw00, paw10, paw01, paw11, pbw00, pbw10, pbw01, pbw11;
  {
    int p;
    p = aBase + 0*128 + 0*64 + r0; if (p > N_TOK-1) p = N_TOK-1; paw00 = (unsigned)p*2048 + keu;
    p = aBase + 1*128 + 0*64 + r0; if (p > N_TOK-1) p = N_TOK-1; paw10 = (unsigned)p*2048 + keu;
    p = aBase + 0*128 + 1*64 + r0; if (p > N_TOK-1) p = N_TOK-1; paw01 = (unsigned)p*2048 + keu;
    p = aBase + 1*128 + 1*64 + r0; if (p > N_TOK-1) p = N_TOK-1; paw11 = (unsigned)p*2048 + keu;
    unsigned int eW = (unsigned)e * (DIM * HID);
    pbw00 = eW + (unsigned)(n0 + 0*128 + 0*64 + r0) * 2048 + keu;
    pbw10 = eW + (unsigned)(n0 + 0*128 + 1*64 + r0) * 2048 + keu;
    pbw01 = eW + (unsigned)(n0 + 1*128 + 0*64 + r0) * 2048 + keu;
    pbw11 = eW + (unsigned)(n0 + 1*128 + 1*64 + r0) * 2048 + keu;
  }

  f32x4 acc[8][4] = {};
  const unsigned short* S0 = sm;
  const unsigned short* S1 = sm + 32768;

  // Prologue: t0 fully (8 loads) + t1.AMh0, t1.Bh0 (4 loads).
  ST_A(0,0,0); ST_B(0,0,0); ST_B(0,1,0); ST_A(0,1,0);
  ST_A(1,0,64); ST_B(1,0,64);
  asm volatile("s_waitcnt vmcnt(4)" ::: "memory");
  BAR();

  short8 fa0, fa1, fa2, fa3;
  short8 bk00, bk01, bk02, bk03;   // B frags @ ksub0
  short8 bk10, bk11, bk12, bk13;   // B frags @ ksub1

#pragma unroll 1
  for (int i = 0; i < NITER; ++i) {
    const int kc = i * 128;
    const bool nl = (i < NITER - 1);

    // ---- phase 1: slot0 (Mh0, K0) ----
    READ_A(S0, 0, cb0);
    READ_B(S0, cb0, bk00, bk01, bk02, bk03);
    ST_B(1,1,kc+64);
    BAR(); PRIO(1);
    QUAD(0, bk00, bk01, bk02, bk03);
    PRIO(0); BAR();

    // ---- phase 2: slot0 (Mh0, K1) ----
    READ_A(S0, 0, cb1);
    READ_B(S0, cb1, bk10, bk11, bk12, bk13);
    ST_A(1,1,kc+64);
    BAR(); PRIO(1);
    QUAD(0, bk10, bk11, bk12, bk13);
    PRIO(0); BAR();

    // ---- phase 3: slot0 (Mh1, K0) ----
    READ_A(S0, 1, cb0);
    if (nl) ST_A(0,0,kc+128);
    BAR(); PRIO(1);
    QUAD(4, bk00, bk01, bk02, bk03);
    PRIO(0); BAR();

    // ---- phase 4: slot0 (Mh1, K1) ----
    READ_A(S0, 1, cb1);
    if (nl) ST_B(0,0,kc+128);
    BAR(); PRIO(1);
    QUAD(4, bk10, bk11, bk12, bk13);
    PRIO(0);
    if (nl) { asm volatile("s_waitcnt vmcnt(4)" ::: "memory"); }
    else    { asm volatile("s_waitcnt vmcnt(0)" ::: "memory"); }
    BAR();

    // ---- phase 5: slot1 (Mh0, K0) ----
    READ_A(S1, 0, cb0);
    READ_B(S1, cb0, bk00, bk01, bk02, bk03);
    if (nl) ST_B(0,1,kc+128);
    BAR(); PRIO(1);
    QUAD(0, bk00, bk01, bk02, bk03);
    PRIO(0); BAR();

    // ---- phase 6: slot1 (Mh0, K1) ----
    READ_A(S1, 0, cb1);
    READ_B(S1, cb1, bk10, bk11, bk12, bk13);
    if (nl) ST_A(0,1,kc+128);
    BAR(); PRIO(1);
    QUAD(0, bk10, bk11, bk12, bk13);
    PRIO(0); BAR();

    // ---- phase 7: slot1 (Mh1, K0) ----
    READ_A(S1, 1, cb0);
    if (nl) ST_A(1,0,kc+192);
    BAR(); PRIO(1);
    QUAD(4, bk00, bk01, bk02, bk03);
    PRIO(0); BAR();

    // ---- phase 8: slot1 (Mh1, K1) ----
    READ_A(S1, 1, cb1);
    if (nl) ST_B(1,0,kc+192);
    BAR(); PRIO(1);
    QUAD(4, bk10, bk11, bk12, bk13);
    PRIO(0);
    if (nl) { asm volatile("s_waitcnt vmcnt(4)" ::: "memory"); }
    BAR();
  }

  // Epilogue: bias + relu, masked tail rows.
#pragma unroll
  for (int n = 0; n < 4; ++n) {
    int col = n0 + wc * 64 + n * 16 + l15;
    float bv = bias[e * HID + col];
#pragma unroll
    for (int m = 0; m < 8; ++m) {
#pragma unroll
      for (int q = 0; q < 4; ++q) {
        int r = wr * 128 + m * 16 + l4 * 4 + q;
        if (mt * 256 + r < cnt) {
          float v = acc[m][n][q] + bv;
          out[(size_t)(off + mt * 256 + r) * HID + col] = v > 0.f ? v : 0.f;
        }
      }
    }
  }
}

// ---------------------------------------------------------------------------
extern "C" void kernel_launch(void* const* d_in, const int* in_sizes, int n_in,
                              void* d_out, int out_size, void* d_ws, size_t ws_size,
                              hipStream_t stream) {
  const float* x   = (const float*)d_in[0];
  const int*   idx = (const int*)d_in[1];
  const float* W   = (const float*)d_in[2];
  const float* b   = (const float*)d_in[3];
  float* out = (float*)d_out;

  char* ws = (char*)d_ws;
  unsigned short* xs = (unsigned short*)ws;                                   // 32 MB
  unsigned short* Wt = (unsigned short*)(ws + (size_t)N_TOK * DIM * 2);       // 64 MB
  int* perm = (int*)(ws + (size_t)N_TOK * DIM * 2 + (size_t)N_EXP * DIM * HID * 2);
  int* offs = perm + N_TOK;

  sort_experts<<<1, 256, 0, stream>>>(idx, perm, offs);
  gather_convert_x<<<N_TOK * (DIM / 8) / 256, 256, 0, stream>>>(x, perm, xs);
  transpose_convert_w<<<dim3(HID / 64, DIM / 64, N_EXP), 256, 0, stream>>>(W, Wt);
  grouped_gemm<<<dim3(HID / 256, N_TOK / 256, N_EXP), 512, 0, stream>>>(xs, Wt, b, offs, out);
}

// Round 4
// 182.642 us; speedup vs baseline: 1.1359x; 1.0722x over previous
//
#include <hip/hip_runtime.h>

// Problem constants
#define N_TOK 8192
#define N_EXP 8
#define DIM   2048
#define HID   2048

typedef __attribute__((ext_vector_type(8))) short short8;
typedef __attribute__((ext_vector_type(4))) float f32x4;
typedef __attribute__((ext_vector_type(4))) unsigned short ushort4v;

__device__ inline unsigned short f2bf(float f) {
  unsigned int u = __builtin_bit_cast(unsigned int, f);
  unsigned int r = u + 0x7FFFu + ((u >> 16) & 1u);   // round-to-nearest-even
  return (unsigned short)(r >> 16);
}

// ---------------------------------------------------------------------------
// Kernel 1: stable counting sort by expert id. One block, 256 threads.
// ---------------------------------------------------------------------------
__global__ __launch_bounds__(256) void sort_experts(const int* __restrict__ idx,
                                                    int* __restrict__ perm,
                                                    int* __restrict__ offs) {
  __shared__ int cnt[256][8];
  __shared__ int base[8];
  const int t = threadIdx.x;
  int local[8] = {0,0,0,0,0,0,0,0};
  const int r0 = t * 32;
  for (int i = 0; i < 32; ++i) {
    int e = idx[r0 + i] & 7;
    ++local[e];
  }
#pragma unroll
  for (int e = 0; e < 8; ++e) cnt[t][e] = local[e];
  __syncthreads();
  if (t < 8) {
    int s = 0;
    for (int i = 0; i < 256; ++i) { int v = cnt[i][t]; cnt[i][t] = s; s += v; }
    base[t] = s;
  }
  __syncthreads();
  if (t == 0) {
    int s = 0;
    for (int e = 0; e < 8; ++e) { int v = base[e]; offs[e] = s; base[e] = s; s += v; }
    offs[8] = s;
  }
  __syncthreads();
  int pos[8];
#pragma unroll
  for (int e = 0; e < 8; ++e) pos[e] = base[e] + cnt[t][e];
  for (int i = 0; i < 32; ++i) {
    int r = r0 + i;
    int e = idx[r] & 7;
    perm[pos[e]++] = r;
  }
}

// ---------------------------------------------------------------------------
// Kernel 2: gather rows into sorted order + fp32 -> bf16.
// ---------------------------------------------------------------------------
__global__ __launch_bounds__(256) void gather_convert_x(const float* __restrict__ x,
                                                        const int* __restrict__ perm,
                                                        unsigned short* __restrict__ xs) {
  int gid = blockIdx.x * 256 + threadIdx.x;
  int p = gid >> 8;
  int c = gid & 255;
  int src = perm[p];
  const float* sp = x + (size_t)src * DIM + c * 8;
  float4 a = *(const float4*)sp;
  float4 b = *(const float4*)(sp + 4);
  short8 o;
  o[0] = (short)f2bf(a.x); o[1] = (short)f2bf(a.y);
  o[2] = (short)f2bf(a.z); o[3] = (short)f2bf(a.w);
  o[4] = (short)f2bf(b.x); o[5] = (short)f2bf(b.y);
  o[6] = (short)f2bf(b.z); o[7] = (short)f2bf(b.w);
  *(short8*)(xs + (size_t)p * DIM + c * 8) = o;
}

// ---------------------------------------------------------------------------
// Kernel 3: W[e][d][h] fp32 -> Wt[e][h][d] bf16 (LDS-tiled transpose).
// ---------------------------------------------------------------------------
__global__ __launch_bounds__(256) void transpose_convert_w(const float* __restrict__ W,
                                                           unsigned short* __restrict__ Wt) {
  __shared__ unsigned short tile[64][68];
  const int e = blockIdx.z;
  const int d0 = blockIdx.y * 64;
  const int h0 = blockIdx.x * 64;
  const int t = threadIdx.x;
  const int cr = t & 15;
  const int rr = t >> 4;
  const float* Wp = W + ((size_t)e * DIM + d0) * HID + h0;
#pragma unroll
  for (int i = 0; i < 4; ++i) {
    int d = rr + i * 16;
    float4 v = *(const float4*)(Wp + (size_t)d * HID + cr * 4);
    ushort4v o;
    o[0] = f2bf(v.x); o[1] = f2bf(v.y); o[2] = f2bf(v.z); o[3] = f2bf(v.w);
    *(ushort4v*)&tile[d][cr * 4] = o;
  }
  __syncthreads();
  unsigned short* op = Wt + ((size_t)e * HID + h0) * DIM + d0;
#pragma unroll
  for (int i = 0; i < 4; ++i) {
    int h = rr + i * 16;
    ushort4v o;
    o[0] = tile[cr * 4 + 0][h];
    o[1] = tile[cr * 4 + 1][h];
    o[2] = tile[cr * 4 + 2][h];
    o[3] = tile[cr * 4 + 3][h];
    *(ushort4v*)(op + (size_t)h * DIM + cr * 4) = o;
  }
}

// ---------------------------------------------------------------------------
// Kernel 4: grouped GEMM — 128(M) x 256(N) tile, BK=64, 8 waves (2M x 4N,
// per-wave 64x64), THREE LDS slots (144 KiB) for a deep pipeline:
// tile T+2 staged during tile T's phases -> uniform 4-phase issue->consume
// slack; vmcnt(6) once per K-tile (2 tiles / 6 loads in flight, m201
// cadence). Phase = full-C x K=32: 8 ds_read_b128 + 3 gload_lds + barrier +
// setprio(1) + 16 MFMA + setprio(0) + barrier. XOR swizzle (byte[6:4] ^=
// row[2:0]) on reads, inverse-applied to global staging sources.
// ---------------------------------------------------------------------------
#define NKT 32          // K-tiles of 64
#define SLOT_USH 24576  // 48KB per slot: A [0,8192) B [8192,24576) ushorts

#define MM(D,A,B) D = __builtin_amdgcn_mfma_f32_16x16x32_bf16(A, B, D, 0, 0, 0)
#define GLD(SRC, DST) __builtin_amdgcn_global_load_lds( \
    (const __attribute__((address_space(1))) void*)(SRC), \
    (__attribute__((address_space(3))) void*)(DST), 16, 0, 0)
#define BAR() __builtin_amdgcn_s_barrier()
#define PRIO(x) __builtin_amdgcn_s_setprio(x)

__global__ __launch_bounds__(512, 2) void grouped_gemm(
    const unsigned short* __restrict__ xs,
    const unsigned short* __restrict__ Wt,
    const float* __restrict__ bias,
    const int* __restrict__ offs,
    float* __restrict__ out) {
  const int e   = blockIdx.z;
  const int off = offs[e];
  const int cnt = offs[e + 1] - off;
  const int mt  = blockIdx.y;
  if (mt * 128 >= cnt) return;
  const int n0 = blockIdx.x * 256;

  __shared__ __align__(16) unsigned short sm[3 * SLOT_USH];   // 144 KiB

  const int t    = threadIdx.x;
  const int lane = t & 63;
  const int wid  = t >> 6;
  const int wr   = wid >> 2;   // 0..1  (M half: rows wr*64)
  const int wc   = wid & 3;    // 0..3  (N quarter: cols wc*64)
  const int l15  = lane & 15;
  const int l4   = lane >> 4;

  // Fragment LDS offsets (ushort units); row stride 64 ush (128B).
  // Swizzle: byte bits[6:4] ^= row[2:0]  ==  ushort k bits[5:3] ^= row[2:0].
  const int cb0  = (l4 * 8) ^ ((l15 & 7) << 3);   // ksub 0
  const int cb1  = cb0 ^ 32;                       // ksub 1
  const int arow = (wr * 64 + l15) * 64;           // + m*1024
  const int brow = 8192 + (wc * 64 + l15) * 64;    // + n*1024

  // Staging sources: chunk thread t covers row r0 = t>>3 (of a 64-row chunk),
  // 16B col (t&7)*16; inverse swizzle pre-applied to global k index.
  const int r0  = t >> 3;
  const int keu = ((t & 7) * 8) ^ ((r0 & 7) << 3);
  const int aBase = off + mt * 128;
  const int dA = t * 8;   // linear LDS dest (ushort) within an 8KB chunk

  unsigned int pa0, pa1, pb0, pb1, pb2, pb3;
  {
    int p;
    p = aBase + 0 * 64 + r0; if (p > N_TOK - 1) p = N_TOK - 1; pa0 = (unsigned)p * 2048 + keu;
    p = aBase + 1 * 64 + r0; if (p > N_TOK - 1) p = N_TOK - 1; pa1 = (unsigned)p * 2048 + keu;
    unsigned int eW = (unsigned)e * (DIM * HID);
    pb0 = eW + (unsigned)(n0 + 0 * 64 + r0) * 2048 + keu;
    pb1 = eW + (unsigned)(n0 + 1 * 64 + r0) * 2048 + keu;
    pb2 = eW + (unsigned)(n0 + 2 * 64 + r0) * 2048 + keu;
    pb3 = eW + (unsigned)(n0 + 3 * 64 + r0) * 2048 + keu;
  }

#define ST_A(SBASE, KOFS) do { \
    GLD(xs + pa0 + (KOFS), sm + (SBASE) + 0 * 4096 + dA); \
    GLD(xs + pa1 + (KOFS), sm + (SBASE) + 1 * 4096 + dA); } while (0)
#define ST_B0(SBASE, KOFS) GLD(Wt + pb0 + (KOFS), sm + (SBASE) + 8192 + 0 * 4096 + dA)
#define ST_B123(SBASE, KOFS) do { \
    GLD(Wt + pb1 + (KOFS), sm + (SBASE) + 8192 + 1 * 4096 + dA); \
    GLD(Wt + pb2 + (KOFS), sm + (SBASE) + 8192 + 2 * 4096 + dA); \
    GLD(Wt + pb3 + (KOFS), sm + (SBASE) + 8192 + 3 * 4096 + dA); } while (0)

#define READ_FRAGS(SP, CB) \
    fa0 = *(const short8*)((SP) + arow + 0 * 1024 + (CB)); \
    fa1 = *(const short8*)((SP) + arow + 1 * 1024 + (CB)); \
    fa2 = *(const short8*)((SP) + arow + 2 * 1024 + (CB)); \
    fa3 = *(const short8*)((SP) + arow + 3 * 1024 + (CB)); \
    fb0 = *(const short8*)((SP) + brow + 0 * 1024 + (CB)); \
    fb1 = *(const short8*)((SP) + brow + 1 * 1024 + (CB)); \
    fb2 = *(const short8*)((SP) + brow + 2 * 1024 + (CB)); \
    fb3 = *(const short8*)((SP) + brow + 3 * 1024 + (CB));

#define MFMA16() \
    MM(acc[0][0],fa0,fb0); MM(acc[0][1],fa0,fb1); MM(acc[0][2],fa0,fb2); MM(acc[0][3],fa0,fb3); \
    MM(acc[1][0],fa1,fb0); MM(acc[1][1],fa1,fb1); MM(acc[1][2],fa1,fb2); MM(acc[1][3],fa1,fb3); \
    MM(acc[2][0],fa2,fb0); MM(acc[2][1],fa2,fb1); MM(acc[2][2],fa2,fb2); MM(acc[2][3],fa2,fb3); \
    MM(acc[3][0],fa3,fb0); MM(acc[3][1],fa3,fb1); MM(acc[3][2],fa3,fb2); MM(acc[3][3],fa3,fb3);

  f32x4 acc[4][4] = {};

  // Prologue: stage tile0 -> slot0, tile1 -> slot1 (6 loads each, A,A,B0,B1,B2,B3).
  ST_A(0, 0); ST_B0(0, 0); ST_B123(0, 0);
  ST_A(SLOT_USH, 64); ST_B0(SLOT_USH, 64); ST_B123(SLOT_USH, 64);
  asm volatile("s_waitcnt vmcnt(6)" ::: "memory");   // tile0 landed
  BAR();

  short8 fa0, fa1, fa2, fa3, fb0, fb1, fb2, fb3;
  int sl = 0;        // slot of tile T       (ushort base = sl*SLOT_USH)
  int s2 = 2;        // slot of tile T+2

#pragma unroll 1
  for (int T = 0; T < NKT; ++T) {
    const unsigned short* SP = sm + sl * SLOT_USH;
    const int sb = s2 * SLOT_USH;
    const int kofs = (T + 2) * 64;
    const bool st = (T < NKT - 2);

    // ---- phase 0: ksub0 ----
    READ_FRAGS(SP, cb0);
    if (st) { ST_A(sb, kofs); ST_B0(sb, kofs); }
    BAR(); PRIO(1);
    MFMA16();
    PRIO(0); BAR();

    // ---- phase 1: ksub1 ----
    READ_FRAGS(SP, cb1);
    if (st) { ST_B123(sb, kofs); }
    BAR(); PRIO(1);
    MFMA16();
    PRIO(0);
    // Counted wait: ensure tile T+1 (staged during iter T-1) has landed.
    // Steady state: 12 outstanding (T-1's 6 + T's 6) -> leave T's 6.
    if (T < NKT - 2)       { asm volatile("s_waitcnt vmcnt(6)" ::: "memory"); }
    else if (T == NKT - 2) { asm volatile("s_waitcnt vmcnt(0)" ::: "memory"); }
    BAR();

    sl = (sl == 2) ? 0 : sl + 1;
    s2 = (s2 == 2) ? 0 : s2 + 1;
  }

  // Epilogue: bias + relu, masked tail rows.
#pragma unroll
  for (int n = 0; n < 4; ++n) {
    int col = n0 + wc * 64 + n * 16 + l15;
    float bv = bias[e * HID + col];
#pragma unroll
    for (int m = 0; m < 4; ++m) {
#pragma unroll
      for (int q = 0; q < 4; ++q) {
        int r = wr * 64 + m * 16 + l4 * 4 + q;
        if (mt * 128 + r < cnt) {
          float v = acc[m][n][q] + bv;
          out[(size_t)(off + mt * 128 + r) * HID + col] = v > 0.f ? v : 0.f;
        }
      }
    }
  }
}

// ---------------------------------------------------------------------------
extern "C" void kernel_launch(void* const* d_in, const int* in_sizes, int n_in,
                              void* d_out, int out_size, void* d_ws, size_t ws_size,
                              hipStream_t stream) {
  const float* x   = (const float*)d_in[0];
  const int*   idx = (const int*)d_in[1];
  const float* W   = (const float*)d_in[2];
  const float* b   = (const float*)d_in[3];
  float* out = (float*)d_out;

  char* ws = (char*)d_ws;
  unsigned short* xs = (unsigned short*)ws;                                   // 32 MB
  unsigned short* Wt = (unsigned short*)(ws + (size_t)N_TOK * DIM * 2);       // 64 MB
  int* perm = (int*)(ws + (size_t)N_TOK * DIM * 2 + (size_t)N_EXP * DIM * HID * 2);
  int* offs = perm + N_TOK;

  sort_experts<<<1, 256, 0, stream>>>(idx, perm, offs);
  gather_convert_x<<<N_TOK * (DIM / 8) / 256, 256, 0, stream>>>(x, perm, xs);
  transpose_convert_w<<<dim3(HID / 64, DIM / 64, N_EXP), 256, 0, stream>>>(W, Wt);
  grouped_gemm<<<dim3(HID / 256, N_TOK / 128, N_EXP), 512, 0, stream>>>(xs, Wt, b, offs, out);
}